// Round 1
// baseline (4735.828 us; speedup 1.0000x reference)
//
#include <hip/hip_runtime.h>
#include <cmath>

#define BGR 2048      // graphs
#define TT  50        // nodes per graph
#define EPG 600       // edges per graph
#define NN  102400    // total nodes
#define EE  1228800   // total edges
#define HH  512       // hidden/out dim
#define BN_EPS 1e-5f

// ---------------- per-graph degree + edge norm ----------------
__global__ __launch_bounds__(256) void norm_kernel(
    const int* __restrict__ ei, const float* __restrict__ ew,
    float* __restrict__ norm, float* __restrict__ nself)
{
    const int g = blockIdx.x, tid = threadIdx.x;
    const int eb = g * EPG, nb = g * TT;
    __shared__ float deg[TT];
    __shared__ float dinv[TT];
    for (int i = tid; i < TT; i += 256) deg[i] = 1.0f;   // self-loop weight
    __syncthreads();
    for (int e = tid; e < EPG; e += 256)
        atomicAdd(&deg[ei[EE + eb + e] - nb], ew[eb + e]);
    __syncthreads();
    for (int i = tid; i < TT; i += 256) {
        float d = deg[i];
        float di = d > 0.0f ? rsqrtf(fmaxf(d, 1e-12f)) : 0.0f;
        dinv[i] = di;
        nself[nb + i] = di * di;
    }
    __syncthreads();
    for (int e = tid; e < EPG; e += 256) {
        int s = ei[eb + e] - nb;
        int d = ei[EE + eb + e] - nb;
        norm[eb + e] = dinv[s] * ew[eb + e] * dinv[d];
    }
}

// ---------------- fp32 tiled GEMM: C[M x 512] = [A | PE(pos)] @ W ----------------
// A: [M x K1] row-major; optional PE gather part: row i uses posemb[pos[i]] ([K2])
// W: [(K1+K2) x 512]. Optional bias + tanh epilogue.
__global__ __launch_bounds__(256) void gemm_kernel(
    const float* __restrict__ A, const float* __restrict__ PE,
    const int* __restrict__ pos, const float* __restrict__ W,
    float* __restrict__ C, int K1, int K2,
    const float* __restrict__ bias, int do_tanh)
{
    __shared__ float As[16][64];
    __shared__ float Bs[16][64];
    const int tid = threadIdx.x;
    const int m0 = blockIdx.y * 64, n0 = blockIdx.x * 64;
    const int K = K1 + K2;
    const int tx = tid & 15, ty = tid >> 4;
    const int lar = tid >> 2, lak = (tid & 3) << 2;   // A tile: 64 rows x 16 k
    const int lbk = tid >> 4, lbn = (tid & 15) << 2;  // B tile: 16 k x 64 n
    float acc[4][4] = {};

    for (int k0 = 0; k0 < K; k0 += 16) {
        const int gm = m0 + lar;
        const int gk = k0 + lak;
        float4 av;
        if (gk < K1) av = *(const float4*)(A + (size_t)gm * K1 + gk);
        else         av = *(const float4*)(PE + (size_t)pos[gm] * K2 + (gk - K1));
        As[lak + 0][lar] = av.x;
        As[lak + 1][lar] = av.y;
        As[lak + 2][lar] = av.z;
        As[lak + 3][lar] = av.w;
        *(float4*)&Bs[lbk][lbn] = *(const float4*)(W + (size_t)(k0 + lbk) * HH + n0 + lbn);
        __syncthreads();
#pragma unroll
        for (int k = 0; k < 16; ++k) {
            float4 a = *(float4*)&As[k][ty << 2];
            float4 b = *(float4*)&Bs[k][tx << 2];
            acc[0][0] = fmaf(a.x, b.x, acc[0][0]);
            acc[0][1] = fmaf(a.x, b.y, acc[0][1]);
            acc[0][2] = fmaf(a.x, b.z, acc[0][2]);
            acc[0][3] = fmaf(a.x, b.w, acc[0][3]);
            acc[1][0] = fmaf(a.y, b.x, acc[1][0]);
            acc[1][1] = fmaf(a.y, b.y, acc[1][1]);
            acc[1][2] = fmaf(a.y, b.z, acc[1][2]);
            acc[1][3] = fmaf(a.y, b.w, acc[1][3]);
            acc[2][0] = fmaf(a.z, b.x, acc[2][0]);
            acc[2][1] = fmaf(a.z, b.y, acc[2][1]);
            acc[2][2] = fmaf(a.z, b.z, acc[2][2]);
            acc[2][3] = fmaf(a.z, b.w, acc[2][3]);
            acc[3][0] = fmaf(a.w, b.x, acc[3][0]);
            acc[3][1] = fmaf(a.w, b.y, acc[3][1]);
            acc[3][2] = fmaf(a.w, b.z, acc[3][2]);
            acc[3][3] = fmaf(a.w, b.w, acc[3][3]);
        }
        __syncthreads();
    }
#pragma unroll
    for (int r = 0; r < 4; ++r) {
        const int gm = m0 + (ty << 2) + r;
        const int gn = n0 + (tx << 2);
        float4 v = make_float4(acc[r][0], acc[r][1], acc[r][2], acc[r][3]);
        if (bias) {
            v.x += bias[gn + 0]; v.y += bias[gn + 1];
            v.z += bias[gn + 2]; v.w += bias[gn + 3];
        }
        if (do_tanh) {
            v.x = tanhf(v.x); v.y = tanhf(v.y);
            v.z = tanhf(v.z); v.w = tanhf(v.w);
        }
        *(float4*)(C + (size_t)gm * HH + gn) = v;
    }
}

// ---------------- per-graph normalized scatter-add (in place on h) + BN stats ----------------
__global__ __launch_bounds__(256) void agg_kernel(
    float* __restrict__ h, const int* __restrict__ ei,
    const float* __restrict__ norm, const float* __restrict__ nself,
    float* __restrict__ stats)
{
    const int g = blockIdx.x, tid = threadIdx.x;
    const int eb = g * EPG, nb = g * TT;
    __shared__ float ht[TT * 256];       // 50 x 256 channel-half tile (51200 B)
    __shared__ float enorm_s[EPG];
    __shared__ int   esrc[EPG];
    __shared__ int   cnt[TT];
    __shared__ int   ofs[TT + 1];
    __shared__ int   cur[TT];

    for (int i = tid; i < TT; i += 256) cnt[i] = 0;
    __syncthreads();
    for (int e = tid; e < EPG; e += 256)
        atomicAdd(&cnt[ei[EE + eb + e] - nb], 1);
    __syncthreads();
    if (tid == 0) {
        int s = 0;
        for (int i = 0; i < TT; ++i) { ofs[i] = s; cur[i] = s; s += cnt[i]; }
        ofs[TT] = s;
    }
    __syncthreads();
    for (int e = tid; e < EPG; e += 256) {
        int sl = ei[eb + e] - nb;
        int dl = ei[EE + eb + e] - nb;
        int p = atomicAdd(&cur[dl], 1);
        esrc[p] = sl;
        enorm_s[p] = norm[eb + e];
    }
    for (int half = 0; half < 2; ++half) {
        __syncthreads();   // protects CSR build (half 0) / previous compute (half 1)
        for (int i = tid; i < TT * 256; i += 256) {
            int r = i >> 8, c = i & 255;
            ht[i] = h[(size_t)(nb + r) * HH + half * 256 + c];
        }
        __syncthreads();
        const int ch = tid;                 // 0..255
        const int gch = half * 256 + ch;
        float sum = 0.0f, sumsq = 0.0f;
        for (int d = 0; d < TT; ++d) {
            float v = nself[nb + d] * ht[d * 256 + ch];
            const int e1 = ofs[d + 1];
            for (int e = ofs[d]; e < e1; ++e)
                v = fmaf(enorm_s[e], ht[esrc[e] * 256 + ch], v);
            h[(size_t)(nb + d) * HH + gch] = v;
            sum += v;
            sumsq = fmaf(v, v, sumsq);
        }
        atomicAdd(&stats[gch], sum);
        atomicAdd(&stats[HH + gch], sumsq);
    }
}

__global__ void zero_stats_kernel(float* __restrict__ s)
{
    const int t = threadIdx.x;
#pragma unroll
    for (int i = 0; i < 4; ++i) s[i * 256 + t] = 0.0f;
}

__global__ void bn_finalize_kernel(
    const float* __restrict__ stats, const float* __restrict__ gamma,
    const float* __restrict__ beta, float* __restrict__ ss)
{
    const int ch = threadIdx.x;   // 512 threads
    const float inv_n = 1.0f / (float)NN;
    float m = stats[ch] * inv_n;
    float v = stats[HH + ch] * inv_n - m * m;
    float sc = gamma[ch] * rsqrtf(v + BN_EPS);
    ss[ch] = sc;
    ss[HH + ch] = beta[ch] - m * sc;
}

__global__ __launch_bounds__(256) void bn_apply_kernel(
    const float* __restrict__ h, const float* __restrict__ ss,
    float* __restrict__ xout, float* __restrict__ res, int first)
{
    const size_t i = ((size_t)blockIdx.x * 256 + threadIdx.x) * 4;
    const int ch = (int)(i & (HH - 1));
    float4 v = *(const float4*)(h + i);
    float4 sc = *(const float4*)(ss + ch);
    float4 sh = *(const float4*)(ss + HH + ch);
    float4 o;
    o.x = fmaxf(0.0f, fmaf(v.x, sc.x, sh.x));
    o.y = fmaxf(0.0f, fmaf(v.y, sc.y, sh.y));
    o.z = fmaxf(0.0f, fmaf(v.z, sc.z, sh.z));
    o.w = fmaxf(0.0f, fmaf(v.w, sc.w, sh.w));
    *(float4*)(xout + i) = o;
    if (first) {
        *(float4*)(res + i) = o;
    } else {
        float4 r = *(const float4*)(res + i);
        r.x += o.x; r.y += o.y; r.z += o.z; r.w += o.w;
        *(float4*)(res + i) = r;
    }
}

extern "C" void kernel_launch(void* const* d_in, const int* in_sizes, int n_in,
                              void* d_out, int out_size, void* d_ws, size_t ws_size,
                              hipStream_t stream) {
    const float* x       = (const float*)d_in[0];
    const int*   ei      = (const int*)d_in[1];
    const float* ew      = (const float*)d_in[2];
    const int*   pos     = (const int*)d_in[3];
    const float* posemb  = (const float*)d_in[4];
    const float* W1      = (const float*)d_in[5];
    // b1/b2/b3 (d_in[6,10,14]) cancel under training-mode BN — skipped.
    const float* g1      = (const float*)d_in[7];
    const float* be1     = (const float*)d_in[8];
    const float* W2      = (const float*)d_in[9];
    const float* g2      = (const float*)d_in[11];
    const float* be2     = (const float*)d_in[12];
    const float* W3      = (const float*)d_in[13];
    const float* g3      = (const float*)d_in[15];
    const float* be3     = (const float*)d_in[16];
    const float* Wl      = (const float*)d_in[17];
    const float* bl      = (const float*)d_in[18];

    float* ws    = (float*)d_ws;
    float* xcur  = ws;                               // NN*HH
    float* res   = xcur + (size_t)NN * HH;           // NN*HH
    float* norm  = res + (size_t)NN * HH;            // EE
    float* nself = norm + EE;                        // NN
    float* stats = nself + NN;                       // 1024 (sum | sumsq)
    float* ss    = stats + 2 * HH;                   // 1024 (scale | shift)

    float* hbuf = (float*)d_out;                     // reuse d_out as h/agg scratch

    const dim3 ggrid(HH / 64, NN / 64);
    const int bn_blocks = (NN * HH) / (256 * 4);

    norm_kernel<<<BGR, 256, 0, stream>>>(ei, ew, norm, nself);

    // layer 1 (concat [x | posemb[pos]] handled inside GEMM)
    gemm_kernel<<<ggrid, 256, 0, stream>>>(x, posemb, pos, W1, hbuf, 512, 64, nullptr, 0);
    zero_stats_kernel<<<1, 256, 0, stream>>>(stats);
    agg_kernel<<<BGR, 256, 0, stream>>>(hbuf, ei, norm, nself, stats);
    bn_finalize_kernel<<<1, 512, 0, stream>>>(stats, g1, be1, ss);
    bn_apply_kernel<<<bn_blocks, 256, 0, stream>>>(hbuf, ss, xcur, res, 1);

    // layer 2
    gemm_kernel<<<ggrid, 256, 0, stream>>>(xcur, nullptr, nullptr, W2, hbuf, 512, 0, nullptr, 0);
    zero_stats_kernel<<<1, 256, 0, stream>>>(stats);
    agg_kernel<<<BGR, 256, 0, stream>>>(hbuf, ei, norm, nself, stats);
    bn_finalize_kernel<<<1, 512, 0, stream>>>(stats, g2, be2, ss);
    bn_apply_kernel<<<bn_blocks, 256, 0, stream>>>(hbuf, ss, xcur, res, 0);

    // layer 3
    gemm_kernel<<<ggrid, 256, 0, stream>>>(xcur, nullptr, nullptr, W3, hbuf, 512, 0, nullptr, 0);
    zero_stats_kernel<<<1, 256, 0, stream>>>(stats);
    agg_kernel<<<BGR, 256, 0, stream>>>(hbuf, ei, norm, nself, stats);
    bn_finalize_kernel<<<1, 512, 0, stream>>>(stats, g3, be3, ss);
    bn_apply_kernel<<<bn_blocks, 256, 0, stream>>>(hbuf, ss, xcur, res, 0);

    // head: out = tanh(res @ Wl + bl); d_out (hbuf) is free to overwrite now
    gemm_kernel<<<ggrid, 256, 0, stream>>>(res, nullptr, nullptr, Wl, hbuf, 512, 0, bl, 1);
}

// Round 3
// 2989.193 us; speedup vs baseline: 1.5843x; 1.5843x over previous
//
#include <hip/hip_runtime.h>
#include <cmath>

#define BGR 2048      // graphs
#define TT  50        // nodes per graph
#define EPG 600       // edges per graph
#define NN  102400    // total nodes
#define EE  1228800   // total edges
#define HH  512       // hidden/out dim
#define BN_EPS 1e-5f

typedef __attribute__((ext_vector_type(8))) short bf16x8;
typedef __attribute__((ext_vector_type(4))) float f32x4;

__device__ __forceinline__ unsigned short f2b(float f) {
    unsigned int u = __float_as_uint(f);
    unsigned int r = (u + 0x7FFFu + ((u >> 16) & 1u)) >> 16;
    return (unsigned short)r;
}
__device__ __forceinline__ float b2f(unsigned short h) {
    return __uint_as_float(((unsigned int)h) << 16);
}
// error-free-ish split: f = hi + lo with hi,lo bf16 (lo·lo-scale loss only)
__device__ __forceinline__ void split2(float f, unsigned short& hi, unsigned short& lo) {
    hi = f2b(f);
    lo = f2b(f - b2f(hi));
}
__device__ __forceinline__ void gload16(const void* g, void* l) {
    __builtin_amdgcn_global_load_lds(
        (const __attribute__((address_space(1))) unsigned int*)g,
        (__attribute__((address_space(3))) unsigned int*)l, 16, 0, 0);
}

// ---------------- per-graph degree + edge norm ----------------
__global__ __launch_bounds__(256) void norm_kernel(
    const int* __restrict__ ei, const float* __restrict__ ew,
    float* __restrict__ norm, float* __restrict__ nself)
{
    const int g = blockIdx.x, tid = threadIdx.x;
    const int eb = g * EPG, nb = g * TT;
    __shared__ float deg[TT];
    __shared__ float dinv[TT];
    for (int i = tid; i < TT; i += 256) deg[i] = 1.0f;   // self-loop weight
    __syncthreads();
    for (int e = tid; e < EPG; e += 256)
        atomicAdd(&deg[ei[EE + eb + e] - nb], ew[eb + e]);
    __syncthreads();
    for (int i = tid; i < TT; i += 256) {
        float d = deg[i];
        float di = d > 0.0f ? rsqrtf(fmaxf(d, 1e-12f)) : 0.0f;
        dinv[i] = di;
        nself[nb + i] = di * di;
    }
    __syncthreads();
    for (int e = tid; e < EPG; e += 256) {
        int s = ei[eb + e] - nb;
        int d = ei[EE + eb + e] - nb;
        norm[eb + e] = dinv[s] * ew[eb + e] * dinv[d];
    }
}

// ---------------- weight convert+transpose+split: W [K x N] fp32 -> Wt hi/lo [N x K] bf16 ----------------
__global__ void wconv_kernel(const float* __restrict__ W,
                             unsigned short* __restrict__ Wh,
                             unsigned short* __restrict__ Wl,
                             int K, int N)
{
    int id = blockIdx.x * 256 + threadIdx.x;
    if (id >= K * N) return;
    int n = id / K, k = id % K;
    split2(W[(size_t)k * N + n], Wh[id], Wl[id]);
}

// ---------------- build layer-1 A: [x | posemb[pos]] -> bf16 hi/lo [NN x 576] ----------------
__global__ __launch_bounds__(256) void build_a1_kernel(
    const float* __restrict__ x, const float* __restrict__ posemb,
    const int* __restrict__ pos,
    unsigned short* __restrict__ Ah, unsigned short* __restrict__ Al)
{
    size_t t = (size_t)blockIdx.x * 256 + threadIdx.x;   // NN*144 threads
    int row = (int)(t / 144);
    int c4 = (int)(t % 144) * 4;
    float4 v;
    if (c4 < 512) v = *(const float4*)(x + (size_t)row * 512 + c4);
    else          v = *(const float4*)(posemb + (size_t)pos[row] * 64 + (c4 - 512));
    ushort4 h, l;
    split2(v.x, h.x, l.x); split2(v.y, h.y, l.y);
    split2(v.z, h.z, l.z); split2(v.w, h.w, l.w);
    *(ushort4*)(Ah + (size_t)row * 576 + c4) = h;
    *(ushort4*)(Al + (size_t)row * 576 + c4) = l;
}

// ---------------- split-bf16 MFMA GEMM (fp32-accurate): C = (Ah+Al) @ (Bh+Bl)^T ----------------
// A,B stored as bf16 hi/lo pairs; Bt is [512 x Kd]. 128x128 tile, BK=32, 16x16x32 MFMA.
// acc += Ah*Bh + Al*Bh + Ah*Bl   (lo*lo dropped: ~2^-18 relative)
__global__ __launch_bounds__(256) void gemm_split_kernel(
    const unsigned short* __restrict__ Ah, const unsigned short* __restrict__ Al,
    const unsigned short* __restrict__ Bh, const unsigned short* __restrict__ Bl,
    float* __restrict__ C, int Kd, const float* __restrict__ bias, int do_tanh)
{
    __shared__ __align__(16) short AsH[128 * 32];
    __shared__ __align__(16) short AsL[128 * 32];
    __shared__ __align__(16) short BsH[128 * 32];
    __shared__ __align__(16) short BsL[128 * 32];
    const int tid = threadIdx.x;
    const int wv = tid >> 6, ln = tid & 63;
    const int m0 = blockIdx.y * 128, n0 = blockIdx.x * 128;
    const int qm = (wv & 1) * 64, qn = (wv >> 1) * 64;

    f32x4 acc[4][4];
#pragma unroll
    for (int i = 0; i < 4; ++i)
#pragma unroll
        for (int j = 0; j < 4; ++j)
            acc[i][j] = (f32x4){0.f, 0.f, 0.f, 0.f};

    const int arow = ln >> 2;            // row within 16-row chunk
    const int ab16 = (ln & 3) * 16;      // byte offset within 64-byte row segment
    const int fr = ln & 15, fq = (ln >> 4) * 8;

    for (int k0 = 0; k0 < Kd; k0 += 32) {
#pragma unroll
        for (int p = 0; p < 2; ++p) {
            const int chunk = p * 4 + wv;
            const int row = chunk * 16 + arow;
            const size_t goff = ((size_t)(m0 + row) * Kd + k0) * 2 + ab16;
            const size_t gofb = ((size_t)(n0 + row) * Kd + k0) * 2 + ab16;
            gload16((const char*)Ah + goff, (char*)AsH + chunk * 1024);
            gload16((const char*)Al + goff, (char*)AsL + chunk * 1024);
            gload16((const char*)Bh + gofb, (char*)BsH + chunk * 1024);
            gload16((const char*)Bl + gofb, (char*)BsL + chunk * 1024);
        }
        __syncthreads();
        bf16x8 ah[4], al[4], bh[4], bl[4];
#pragma unroll
        for (int i = 0; i < 4; ++i) {
            const int ra = (qm + i * 16 + fr) * 32 + fq;
            const int rb = (qn + i * 16 + fr) * 32 + fq;
            ah[i] = *(const bf16x8*)&AsH[ra];
            al[i] = *(const bf16x8*)&AsL[ra];
            bh[i] = *(const bf16x8*)&BsH[rb];
            bl[i] = *(const bf16x8*)&BsL[rb];
        }
#pragma unroll
        for (int mi = 0; mi < 4; ++mi)
#pragma unroll
            for (int ni = 0; ni < 4; ++ni) {
                acc[mi][ni] = __builtin_amdgcn_mfma_f32_16x16x32_bf16(
                    ah[mi], bh[ni], acc[mi][ni], 0, 0, 0);
                acc[mi][ni] = __builtin_amdgcn_mfma_f32_16x16x32_bf16(
                    al[mi], bh[ni], acc[mi][ni], 0, 0, 0);
                acc[mi][ni] = __builtin_amdgcn_mfma_f32_16x16x32_bf16(
                    ah[mi], bl[ni], acc[mi][ni], 0, 0, 0);
            }
        __syncthreads();
    }

    const int col = ln & 15, rbase = (ln >> 4) * 4;
#pragma unroll
    for (int mi = 0; mi < 4; ++mi) {
#pragma unroll
        for (int ni = 0; ni < 4; ++ni) {
            const int gn = n0 + qn + ni * 16 + col;
            const float bv = bias ? bias[gn] : 0.0f;
#pragma unroll
            for (int r = 0; r < 4; ++r) {
                const int gm = m0 + qm + mi * 16 + rbase + r;
                float v = acc[mi][ni][r] + bv;
                if (do_tanh) v = tanhf(v);
                C[(size_t)gm * HH + gn] = v;
            }
        }
    }
}

// ---------------- per-graph normalized scatter-add (in place on h) + BN stats ----------------
__global__ __launch_bounds__(256) void agg_kernel(
    float* __restrict__ h, const int* __restrict__ ei,
    const float* __restrict__ norm, const float* __restrict__ nself,
    float* __restrict__ stats)
{
    const int g = blockIdx.x, tid = threadIdx.x;
    const int eb = g * EPG, nb = g * TT;
    __shared__ float ht[TT * 256];       // 50 x 256 channel-half tile (51200 B)
    __shared__ float enorm_s[EPG];
    __shared__ int   esrc[EPG];
    __shared__ int   cnt[TT];
    __shared__ int   ofs[TT + 1];
    __shared__ int   cur[TT];

    for (int i = tid; i < TT; i += 256) cnt[i] = 0;
    __syncthreads();
    for (int e = tid; e < EPG; e += 256)
        atomicAdd(&cnt[ei[EE + eb + e] - nb], 1);
    __syncthreads();
    if (tid == 0) {
        int s = 0;
        for (int i = 0; i < TT; ++i) { ofs[i] = s; cur[i] = s; s += cnt[i]; }
        ofs[TT] = s;
    }
    __syncthreads();
    for (int e = tid; e < EPG; e += 256) {
        int sl = ei[eb + e] - nb;
        int dl = ei[EE + eb + e] - nb;
        int p = atomicAdd(&cur[dl], 1);
        esrc[p] = sl;
        enorm_s[p] = norm[eb + e];
    }
    for (int half = 0; half < 2; ++half) {
        __syncthreads();
        for (int i = tid; i < TT * 256; i += 256) {
            int r = i >> 8, c = i & 255;
            ht[i] = h[(size_t)(nb + r) * HH + half * 256 + c];
        }
        __syncthreads();
        const int ch = tid;
        const int gch = half * 256 + ch;
        float sum = 0.0f, sumsq = 0.0f;
        for (int d = 0; d < TT; ++d) {
            float v = nself[nb + d] * ht[d * 256 + ch];
            const int e1 = ofs[d + 1];
            for (int e = ofs[d]; e < e1; ++e)
                v = fmaf(enorm_s[e], ht[esrc[e] * 256 + ch], v);
            h[(size_t)(nb + d) * HH + gch] = v;
            sum += v;
            sumsq = fmaf(v, v, sumsq);
        }
        atomicAdd(&stats[gch], sum);
        atomicAdd(&stats[HH + gch], sumsq);
    }
}

__global__ void zero_stats_kernel(float* __restrict__ s)
{
    const int t = threadIdx.x;
#pragma unroll
    for (int i = 0; i < 4; ++i) s[i * 256 + t] = 0.0f;
}

__global__ void bn_finalize_kernel(
    const float* __restrict__ stats, const float* __restrict__ gamma,
    const float* __restrict__ beta, float* __restrict__ ss)
{
    const int ch = threadIdx.x;   // 512 threads
    const float inv_n = 1.0f / (float)NN;
    float m = stats[ch] * inv_n;
    float v = stats[HH + ch] * inv_n - m * m;
    float sc = gamma[ch] * rsqrtf(v + BN_EPS);
    ss[ch] = sc;
    ss[HH + ch] = beta[ch] - m * sc;
}

// BN+ReLU. mode 1: res=o, write split(o). mode 0: res+=o, write split(o).
// mode 2: r=res+o, write split(r) (final residual for head GEMM).
__global__ __launch_bounds__(256) void bn_apply_kernel(
    const float* __restrict__ h, const float* __restrict__ ss,
    unsigned short* __restrict__ xh, unsigned short* __restrict__ xl,
    float* __restrict__ resf, int mode)
{
    const size_t i = ((size_t)blockIdx.x * 256 + threadIdx.x) * 4;
    const int ch = (int)(i & (HH - 1));
    float4 v = *(const float4*)(h + i);
    float4 sc = *(const float4*)(ss + ch);
    float4 sh = *(const float4*)(ss + HH + ch);
    float4 o;
    o.x = fmaxf(0.0f, fmaf(v.x, sc.x, sh.x));
    o.y = fmaxf(0.0f, fmaf(v.y, sc.y, sh.y));
    o.z = fmaxf(0.0f, fmaf(v.z, sc.z, sh.z));
    o.w = fmaxf(0.0f, fmaf(v.w, sc.w, sh.w));
    if (mode == 1) {
        *(float4*)(resf + i) = o;
    } else if (mode == 0) {
        float4 r = *(const float4*)(resf + i);
        r.x += o.x; r.y += o.y; r.z += o.z; r.w += o.w;
        *(float4*)(resf + i) = r;
    } else {
        float4 r = *(const float4*)(resf + i);
        o.x += r.x; o.y += r.y; o.z += r.z; o.w += r.w;
    }
    ushort4 oh, ol;
    split2(o.x, oh.x, ol.x); split2(o.y, oh.y, ol.y);
    split2(o.z, oh.z, ol.z); split2(o.w, oh.w, ol.w);
    *(ushort4*)(xh + i) = oh;
    *(ushort4*)(xl + i) = ol;
}

extern "C" void kernel_launch(void* const* d_in, const int* in_sizes, int n_in,
                              void* d_out, int out_size, void* d_ws, size_t ws_size,
                              hipStream_t stream) {
    const float* x       = (const float*)d_in[0];
    const int*   ei      = (const int*)d_in[1];
    const float* ew      = (const float*)d_in[2];
    const int*   pos     = (const int*)d_in[3];
    const float* posemb  = (const float*)d_in[4];
    const float* W1      = (const float*)d_in[5];
    // b1/b2/b3 (d_in[6,10,14]) cancel under training-mode BN — skipped.
    const float* g1      = (const float*)d_in[7];
    const float* be1     = (const float*)d_in[8];
    const float* W2      = (const float*)d_in[9];
    const float* g2      = (const float*)d_in[11];
    const float* be2     = (const float*)d_in[12];
    const float* W3      = (const float*)d_in[13];
    const float* g3      = (const float*)d_in[15];
    const float* be3     = (const float*)d_in[16];
    const float* Wl      = (const float*)d_in[17];
    const float* bl      = (const float*)d_in[18];

    // workspace layout (bytes). Region R1 (2 x NN x 576 bf16) is reused:
    //   phase 1: A1 hi/lo (layer-1 GEMM input)
    //   phase 2: xcur hi/lo (layer-2/3 GEMM input)
    //   phase 3: res hi/lo (head GEMM input)
    char* w = (char*)d_ws;
    unsigned short* R1 = (unsigned short*)w;          w += (size_t)NN * 576 * 2 * 2;
    float* resf  = (float*)w;                         w += (size_t)NN * HH * 4;
    float* norm  = (float*)w;                         w += (size_t)EE * 4;
    float* nself = (float*)w;                         w += (size_t)NN * 4;
    float* stats = (float*)w;                         w += 1024 * 4;
    float* ss    = (float*)w;                         w += 1024 * 4;
    unsigned short* W1h = (unsigned short*)w;         w += (size_t)512 * 576 * 2;
    unsigned short* W1l = (unsigned short*)w;         w += (size_t)512 * 576 * 2;
    unsigned short* W2h = (unsigned short*)w;         w += (size_t)512 * 512 * 2;
    unsigned short* W2l = (unsigned short*)w;         w += (size_t)512 * 512 * 2;
    unsigned short* W3h = (unsigned short*)w;         w += (size_t)512 * 512 * 2;
    unsigned short* W3l = (unsigned short*)w;         w += (size_t)512 * 512 * 2;
    unsigned short* Wlh = (unsigned short*)w;         w += (size_t)512 * 512 * 2;
    unsigned short* Wll = (unsigned short*)w;         w += (size_t)512 * 512 * 2;

    unsigned short* A1h = R1;
    unsigned short* A1l = R1 + (size_t)NN * 576;
    unsigned short* xch = R1;                         // reuse after layer-1 GEMM
    unsigned short* xcl = R1 + (size_t)NN * HH;

    float* hbuf = (float*)d_out;                      // reuse d_out as h/agg scratch

    const dim3 ggrid(HH / 128, NN / 128);
    const int bn_blocks = (NN * HH) / (256 * 4);

    norm_kernel<<<BGR, 256, 0, stream>>>(ei, ew, norm, nself);
    wconv_kernel<<<(576 * 512 + 255) / 256, 256, 0, stream>>>(W1, W1h, W1l, 576, 512);
    wconv_kernel<<<(512 * 512 + 255) / 256, 256, 0, stream>>>(W2, W2h, W2l, 512, 512);
    wconv_kernel<<<(512 * 512 + 255) / 256, 256, 0, stream>>>(W3, W3h, W3l, 512, 512);
    wconv_kernel<<<(512 * 512 + 255) / 256, 256, 0, stream>>>(Wl, Wlh, Wll, 512, 512);
    build_a1_kernel<<<(NN * 144) / 256, 256, 0, stream>>>(x, posemb, pos, A1h, A1l);

    // layer 1
    gemm_split_kernel<<<ggrid, 256, 0, stream>>>(A1h, A1l, W1h, W1l, hbuf, 576, nullptr, 0);
    zero_stats_kernel<<<1, 256, 0, stream>>>(stats);
    agg_kernel<<<BGR, 256, 0, stream>>>(hbuf, ei, norm, nself, stats);
    bn_finalize_kernel<<<1, 512, 0, stream>>>(stats, g1, be1, ss);
    bn_apply_kernel<<<bn_blocks, 256, 0, stream>>>(hbuf, ss, xch, xcl, resf, 1);

    // layer 2
    gemm_split_kernel<<<ggrid, 256, 0, stream>>>(xch, xcl, W2h, W2l, hbuf, 512, nullptr, 0);
    zero_stats_kernel<<<1, 256, 0, stream>>>(stats);
    agg_kernel<<<BGR, 256, 0, stream>>>(hbuf, ei, norm, nself, stats);
    bn_finalize_kernel<<<1, 512, 0, stream>>>(stats, g2, be2, ss);
    bn_apply_kernel<<<bn_blocks, 256, 0, stream>>>(hbuf, ss, xch, xcl, resf, 0);

    // layer 3 (mode 2: xch/xcl receive split of final residual for the head)
    gemm_split_kernel<<<ggrid, 256, 0, stream>>>(xch, xcl, W3h, W3l, hbuf, 512, nullptr, 0);
    zero_stats_kernel<<<1, 256, 0, stream>>>(stats);
    agg_kernel<<<BGR, 256, 0, stream>>>(hbuf, ei, norm, nself, stats);
    bn_finalize_kernel<<<1, 512, 0, stream>>>(stats, g3, be3, ss);
    bn_apply_kernel<<<bn_blocks, 256, 0, stream>>>(hbuf, ss, xch, xcl, resf, 2);

    // head: out = tanh(res @ Wl + bl)
    gemm_split_kernel<<<ggrid, 256, 0, stream>>>(xch, xcl, Wlh, Wll, (float*)d_out, 512, bl, 1);
}